// Round 5
// baseline (434.000 us; speedup 1.0000x reference)
//
#include <hip/hip_runtime.h>

#define KNEIGH 16
#define FDIM   128

typedef float f32x4 __attribute__((ext_vector_type(4)));

// One HALF-WAVE (32 lanes) per batch row; each wave covers two consecutive
// rows (2r for lanes 0-31, 2r+1 for lanes 32-63). Each lane owns one float4
// (16 B) slice of the 512 B feature row, so every global_load_dwordx4
// fetches two full feature rows (1 KB/instr), 16 gathers per wave.
//
// This round: occupancy experiment.
//  - #pragma unroll 4 caps in-flight load destinations at 16 VGPRs (the
//    full unroll kept 16 loads = 64 dest VGPRs live, likely pushing total
//    VGPR past the 64-reg cliff -> half occupancy).
//  - __launch_bounds__(256, 8) asks for 8 waves/SIMD (32 waves/CU), forcing
//    the allocator to stay <= 64 VGPR.
__global__ __launch_bounds__(256, 8) void WeightedAggregator_89489938580183_kernel(
    const float* __restrict__ features,   // [N, 128]
    const float* __restrict__ neigh_w,    // [B, 16]
    const int*   __restrict__ neigh_idx,  // [B, 16] (int32 per harness)
    float*       __restrict__ out,        // [B, 128]
    int batch) {

    const int lane = threadIdx.x & 63;
    int wid = blockIdx.x * (blockDim.x >> 6) + (threadIdx.x >> 6);
    int rowA = wid * 2;
    if (rowA >= batch) return;
    rowA = __builtin_amdgcn_readfirstlane(rowA);       // wave-uniform
    const int rowB = (rowA + 1 < batch) ? rowA + 1 : rowA;  // tail clamp

    // Scalar (SGPR) loads: two rows' weights / indices.
    const float* wpA = neigh_w   + (size_t)rowA * KNEIGH;
    const float* wpB = neigh_w   + (size_t)rowB * KNEIGH;
    const int*   ipA = neigh_idx + (size_t)rowA * KNEIGH;
    const int*   ipB = neigh_idx + (size_t)rowB * KNEIGH;

    float wA[KNEIGH], wB[KNEIGH];
    int   iA[KNEIGH], iB[KNEIGH];
    #pragma unroll
    for (int k = 0; k < KNEIGH; ++k) {
        wA[k] = wpA[k]; wB[k] = wpB[k];
        iA[k] = ipA[k]; iB[k] = ipB[k];
    }

    // Uniform per-row weight sums -> per-row 1/sum.
    float sA = wA[0], sB = wB[0];
    #pragma unroll
    for (int k = 1; k < KNEIGH; ++k) { sA += wA[k]; sB += wB[k]; }
    const float invA = 1.0f / sA;
    const float invB = 1.0f / sB;

    const int half = lane >> 5;   // 0 -> rowA, 1 -> rowB
    const int sub  = lane & 31;   // float4 column quad owned
    const float inv = half ? invB : invA;

    // Dual accumulators break the serial FMA dependence chain.
    f32x4 acc0 = (f32x4)(0.0f);
    f32x4 acc1 = (f32x4)(0.0f);

    // Pipeline depth 4 (2 iterations x 2 loads): 16 dest VGPRs in flight.
    #pragma unroll 4
    for (int k = 0; k < KNEIGH; k += 2) {
        const int   i0 = half ? iB[k]     : iA[k];
        const int   i1 = half ? iB[k + 1] : iA[k + 1];
        const float w0 = (half ? wB[k]     : wA[k])     * inv;
        const float w1 = (half ? wB[k + 1] : wA[k + 1]) * inv;

        // 32-bit zext voffset: SGPR base + (idx*512B + sub*16B).
        const f32x4 f0 = ((const f32x4*)features)[((unsigned)i0 << 5) + sub];
        const f32x4 f1 = ((const f32x4*)features)[((unsigned)i1 << 5) + sub];

        acc0 += w0 * f0;
        acc1 += w1 * f1;
    }

    const f32x4 acc = acc0 + acc1;

    // 1 KB fully-coalesced wave store (rows 2r, 2r+1 contiguous).
    const int orow = rowA + half;
    if (orow < batch) {
        f32x4* dst = (f32x4*)(out + (size_t)orow * FDIM) + sub;
        *dst = acc;
    }
}

extern "C" void kernel_launch(void* const* d_in, const int* in_sizes, int n_in,
                              void* d_out, int out_size, void* d_ws, size_t ws_size,
                              hipStream_t stream) {
    const float* features  = (const float*)d_in[0];
    const float* neigh_w   = (const float*)d_in[1];
    const int*   neigh_idx = (const int*)d_in[2];
    float*       out       = (float*)d_out;

    const int batch = in_sizes[1] / KNEIGH;      // 50000

    // One wave per TWO rows; 4 waves per 256-thread block.
    const int rows_per_block = 2 * (256 / 64);
    const int blocks = (batch + rows_per_block - 1) / rows_per_block;
    WeightedAggregator_89489938580183_kernel<<<blocks, 256, 0, stream>>>(
        features, neigh_w, neigh_idx, out, batch);
}

// Round 7
// 400.607 us; speedup vs baseline: 1.0834x; 1.0834x over previous
//
#include <hip/hip_runtime.h>

#define KNEIGH 16
#define FDIM   128

typedef float f32x4 __attribute__((ext_vector_type(4)));

// FOUR rows per wave: 16 lanes per row (group g = lane>>4), each lane owns a
// 32 B slice (two float4s) of its row. Per neighbor k, the wave issues TWO
// global_load_dwordx4 (each covering 4 rows x 256 B = 1 KB) -> 32 load
// instructions in flight per wave, double R4's 16. This is a direct test of
// the per-wave MLP lever that R5 proved dominant (occupancy 78% + 4-deep
// pipeline LOST to occupancy ~50% + 16-deep by 24%).
//
// Weights/indices: lane (g,ell) loads the (row g, neighbor ell) pair --
// one fully-coalesced 256 B wave load each. Per-group weight sum via
// xor-shuffles 1/2/4/8 (stays within the 16-lane group). Broadcast of
// (w,idx) for neighbor k via ds_bpermute from lane (g*16+k) -- off the
// vmem path, doesn't consume request-queue slots.
__global__ __launch_bounds__(256) void WeightedAggregator_89489938580183_kernel(
    const float* __restrict__ features,   // [N, 128]
    const float* __restrict__ neigh_w,    // [B, 16]
    const int*   __restrict__ neigh_idx,  // [B, 16] (int32 per harness)
    float*       __restrict__ out,        // [B, 128]
    int batch) {

    const int lane = threadIdx.x & 63;
    int wid = blockIdx.x * (blockDim.x >> 6) + (threadIdx.x >> 6);
    int r0 = wid * 4;
    if (r0 >= batch) return;
    r0 = __builtin_amdgcn_readfirstlane(r0);   // wave-uniform

    const int g   = lane >> 4;    // row within the wave's 4-row pack
    const int ell = lane & 15;    // lane within group; also neighbor id held

    // Per-lane row (tail-clamped; batch%4==0 so normally exact).
    const int myrow = (r0 + g < batch) ? r0 + g : batch - 1;

    // One coalesced 256 B load each: lane (g,ell) holds (w, idx) of
    // (row g, neighbor ell).
    const float wv = neigh_w  [(size_t)myrow * KNEIGH + ell];
    const int   iv = neigh_idx[(size_t)myrow * KNEIGH + ell];

    // Per-group weight sum (xor 1,2,4,8 stays inside the 16-lane group).
    float s = wv;
    s += __shfl_xor(s, 1);
    s += __shfl_xor(s, 2);
    s += __shfl_xor(s, 4);
    s += __shfl_xor(s, 8);
    const float inv = 1.0f / s;          // uniform within each group

    const int gbase = lane & 48;         // first lane of this group

    f32x4 acc0 = (f32x4)(0.0f);          // floats [ell*8 .. ell*8+3]
    f32x4 acc1 = (f32x4)(0.0f);          // floats [ell*8+4 .. ell*8+7]

    #pragma unroll
    for (int k = 0; k < KNEIGH; ++k) {
        const float wk = __shfl(wv, gbase + k) * inv;   // group's weight k
        const int   ik = __shfl(iv, gbase + k);         // group's index k

        // 32-bit zext voffset: idx*512 B + ell*32 B, in float4 units.
        const unsigned off = ((unsigned)ik << 5) + (unsigned)(ell << 1);
        const f32x4 f0 = ((const f32x4*)features)[off];
        const f32x4 f1 = ((const f32x4*)features)[off + 1];

        acc0 += wk * f0;
        acc1 += wk * f1;
    }

    // 4 output rows are contiguous: wave writes 2 KB fully coalesced
    // (each lane: 32 B via two dwordx4).
    if (r0 + g < batch) {
        f32x4* dst = (f32x4*)out + ((size_t)(r0 + g) << 5) + (ell << 1);
        dst[0] = acc0;
        dst[1] = acc1;
    }
}

extern "C" void kernel_launch(void* const* d_in, const int* in_sizes, int n_in,
                              void* d_out, int out_size, void* d_ws, size_t ws_size,
                              hipStream_t stream) {
    const float* features  = (const float*)d_in[0];
    const float* neigh_w   = (const float*)d_in[1];
    const int*   neigh_idx = (const int*)d_in[2];
    float*       out       = (float*)d_out;

    const int batch = in_sizes[1] / KNEIGH;      // 50000

    // One wave per FOUR rows; 4 waves per 256-thread block.
    const int rows_per_block = 4 * (256 / 64);
    const int blocks = (batch + rows_per_block - 1) / rows_per_block;
    WeightedAggregator_89489938580183_kernel<<<blocks, 256, 0, stream>>>(
        features, neigh_w, neigh_idx, out, batch);
}